// Round 2
// baseline (1096.981 us; speedup 1.0000x reference)
//
#include <hip/hip_runtime.h>

#define TT 512
#define BB 256
#define DD 2048
#define DQ 2049   // D + Q (Q == 1)

// ---- fast transcendentals (v_exp_f32 / v_rcp_f32) -------------------------
__device__ __forceinline__ float fexp(float x) {
    return exp2f(x * 1.442695040888963f);      // e^x = 2^(x*log2 e)
}
__device__ __forceinline__ float frcp(float x) {
    return __builtin_amdgcn_rcpf(x);
}
__device__ __forceinline__ float ftanh(float x) {
    return 1.f - 2.f * frcp(1.f + fexp(2.f * x));
}
__device__ __forceinline__ float fsig(float x) {
    return frcp(1.f + fexp(-x));
}

__device__ __forceinline__ void wait8(const int* cnt, int t0) {
#pragma unroll
    for (int j = 0; j < 8; ++j) {
        while (__hip_atomic_load(cnt + t0 + j, __ATOMIC_ACQUIRE,
                                 __HIP_MEMORY_SCOPE_AGENT) < 16) {
            __builtin_amdgcn_s_sleep(2);
        }
    }
}

// One fused kernel.
//   block 0          : sequential LSTM scan (consumer), polls cnt[t]
//   blocks 1..2048   : skinny GEMM producers; wave gw owns rows
//                      [gw*16, gw*16+16) (all inside t = gw>>4)
__global__ __launch_bounds__(256, 4) void qlstm_fused(
    const float* __restrict__ x,    // [T*B, 2048]
    const float* __restrict__ lw,   // [4, 2049]
    const float* __restrict__ lb,   // [4]
    const float* __restrict__ ew,   // [4]
    const float* __restrict__ ebv,  // [4]
    const float* __restrict__ rx,   // [4]
    const float* __restrict__ mw,   // [4]
    const float* __restrict__ mb,   // [4]
    float* __restrict__ pre,        // ws: [T*B, 4]
    int* __restrict__ cnt,          // ws: [T], zeroed before launch
    float* __restrict__ out)        // [T*B + B + B]
{
    __shared__ float4 wlds[2048];   // 32 KB: [it 0..7][g 0..3][lane 0..63]

    if (blockIdx.x != 0) {
        // ---------------- GEMM producer ----------------
        float* wldsf = (float*)wlds;
        // dest flat j = it*1024 + g*256 + (l*4+c); src = g*DQ + it*256 + (j&255)
        for (int j = threadIdx.x; j < 8192; j += 256) {
            const int g  = (j >> 8) & 3;
            const int it = j >> 10;
            wldsf[j] = lw[g * DQ + it * 256 + (j & 255)];
        }
        __syncthreads();

        const int lane = threadIdx.x & 63;
        const int gw   = (blockIdx.x - 1) * 4 + (threadIdx.x >> 6);  // 0..8191
        const int t    = gw >> 4;
        const int g4   = (lane >> 2) & 3;
        const float lbg = lb[g4];

        const float* xb = x + (size_t)gw * 16 * DD + lane * 4;

        float4 xv[8], xn[8];
#pragma unroll
        for (int j = 0; j < 8; ++j)
            xv[j] = *reinterpret_cast<const float4*>(xb + j * 256);

        for (int r = 0; r < 16; ++r) {
            if (r < 15) {
#pragma unroll
                for (int j = 0; j < 8; ++j)
                    xn[j] = *reinterpret_cast<const float4*>(xb + (r + 1) * DD + j * 256);
            }
            float a0 = 0.f, a1 = 0.f, a2 = 0.f, a3 = 0.f;
#pragma unroll
            for (int it = 0; it < 8; ++it) {
                const float4 xvv = xv[it];
                const float4 w0 = wlds[(it * 4 + 0) * 64 + lane];
                const float4 w1 = wlds[(it * 4 + 1) * 64 + lane];
                const float4 w2 = wlds[(it * 4 + 2) * 64 + lane];
                const float4 w3 = wlds[(it * 4 + 3) * 64 + lane];
                a0 += xvv.x * w0.x + xvv.y * w0.y + xvv.z * w0.z + xvv.w * w0.w;
                a1 += xvv.x * w1.x + xvv.y * w1.y + xvv.z * w1.z + xvv.w * w1.w;
                a2 += xvv.x * w2.x + xvv.y * w2.y + xvv.z * w2.z + xvv.w * w2.w;
                a3 += xvv.x * w3.x + xvv.y * w3.y + xvv.z * w3.z + xvv.w * w3.w;
            }
            // 4-stage butterfly on 4 accs (lanes ≡ mod 4 hold class sums)
#pragma unroll
            for (int s = 32; s >= 4; s >>= 1) {
                a0 += __shfl_xor(a0, s);
                a1 += __shfl_xor(a1, s);
                a2 += __shfl_xor(a2, s);
                a3 += __shfl_xor(a3, s);
            }
            // quad q handles gate q&3: pick its class partial, sum the quad
            float v  = (g4 & 1) ? a1 : a0;
            float v2 = (g4 & 1) ? a3 : a2;
            v = (g4 & 2) ? v2 : v;
            v += __shfl_xor(v, 1);
            v += __shfl_xor(v, 2);
            if ((lane & 3) == 0 && lane < 16)
                pre[(size_t)(gw * 16 + r) * 4 + (lane >> 2)] = v + lbg;
#pragma unroll
            for (int j = 0; j < 8; ++j) xv[j] = xn[j];
        }
        __threadfence();                       // release pre stores
        if (lane == 0) atomicAdd(&cnt[t], 1);  // 16 waves per t
        return;
    }

    // ---------------- scan consumer (block 0) ----------------
    const int b = threadIdx.x;
    const float4* pre4 = (const float4*)pre;

    float whx[4], al[4], be[4], mww[4], mbb[4];
#pragma unroll
    for (int g = 0; g < 4; ++g) {
        whx[g] = lw[g * DQ + DD];
        al[g]  = rx[g] * ew[g];
        be[g]  = rx[g] * ebv[g];
        mww[g] = mw[g];
        mbb[g] = mb[g];
    }

    float h = 0.f, c = 0.f;
    float4 cur[8], nxt[8];

    wait8(cnt, 0);
#pragma unroll
    for (int j = 0; j < 8; ++j) cur[j] = pre4[j * BB + b];

    for (int t0 = 0; t0 < TT; t0 += 8) {
        const int tn = t0 + 8;
        if (tn < TT) {
            wait8(cnt, tn);
#pragma unroll
            for (int j = 0; j < 8; ++j) nxt[j] = pre4[(tn + j) * BB + b];
        }
#pragma unroll
        for (int j = 0; j < 8; ++j) {
            const float4 pc = cur[j];
            const float p0 = pc.x + h * whx[0];
            const float p1 = pc.y + h * whx[1];
            const float p2 = pc.z + h * whx[2];
            const float p3 = pc.w + h * whx[3];
            const float s0 = ftanh(al[0] * p0 + be[0]);
            const float s1 = ftanh(al[1] * p1 + be[1]);
            const float s2 = ftanh(al[2] * p2 + be[2]);
            const float s3 = ftanh(al[3] * p3 + be[3]);
            const float v0 = s0 * mww[0] + mbb[0];
            const float v1 = s1 * mww[1] + mbb[1];
            const float v2 = s2 * mww[2] + mbb[2];
            const float v3 = s3 * mww[3] + mbb[3];
            const float f  = fsig(v0);
            const float i  = fsig(v1);
            const float gg = ftanh(v2);
            const float o  = fsig(v3);
            c = f * c + i * gg;
            h = o * ftanh(c);
            out[(t0 + j) * BB + b] = h;
        }
#pragma unroll
        for (int j = 0; j < 8; ++j) cur[j] = nxt[j];
    }

    out[TT * BB + b]      = h;
    out[TT * BB + BB + b] = c;
}

extern "C" void kernel_launch(void* const* d_in, const int* in_sizes, int n_in,
                              void* d_out, int out_size, void* d_ws, size_t ws_size,
                              hipStream_t stream) {
    const float* x   = (const float*)d_in[0];
    const float* lw  = (const float*)d_in[1];
    const float* lb  = (const float*)d_in[2];
    const float* ew  = (const float*)d_in[3];
    const float* ebv = (const float*)d_in[4];
    const float* rx  = (const float*)d_in[5];
    const float* mw  = (const float*)d_in[6];
    const float* mb  = (const float*)d_in[7];
    float* out = (float*)d_out;

    int*   cnt = (int*)d_ws;                          // 512 ints (2 KB)
    float* pre = (float*)((char*)d_ws + 4096);        // 2 MiB

    hipMemsetAsync(d_ws, 0, 2048, stream);            // zero flags (capturable)
    qlstm_fused<<<2049, 256, 0, stream>>>(x, lw, lb, ew, ebv, rx, mw, mb,
                                          pre, cnt, out);
}

// Round 3
// 350.726 us; speedup vs baseline: 3.1277x; 3.1277x over previous
//
#include <hip/hip_runtime.h>

#define TT 512
#define BB 256
#define DD 2048
#define DQ 2049   // D + Q (Q == 1)

// ---- fast transcendentals (v_exp_f32 / v_rcp_f32) -------------------------
__device__ __forceinline__ float fexp(float x) {
    return exp2f(x * 1.442695040888963f);      // e^x = 2^(x*log2 e)
}
__device__ __forceinline__ float frcp(float x) {
    return __builtin_amdgcn_rcpf(x);
}
__device__ __forceinline__ float ftanh(float x) {
    return 1.f - 2.f * frcp(1.f + fexp(2.f * x));
}
__device__ __forceinline__ float fsig(float x) {
    return frcp(1.f + fexp(-x));
}

// ---- Kernel 1: pre[row][g] = dot(x[row,:2048], lw[g,:2048]) + lb[g] -------
// Weights in LDS (32 KB, conflict-free b128 layout — 0 conflicts measured in
// round 2). Each wave owns 16 consecutive rows, processed in groups of 4 so
// one 16-accumulator xor-butterfly amortizes over 4 rows. x loads are
// double-buffered across `it` AND across the reduction (at it==7 we prefetch
// the next group's first chunk), so 4 float4 loads stay in flight through
// the butterfly. VGPR ≈ 100 → 4-5 waves/SIMD (vs 2 in round 1 with
// register-resident weights).
__global__ __launch_bounds__(256) void qlstm_gemm(
    const float* __restrict__ x,    // [T*B, 2048]
    const float* __restrict__ lw,   // [4, 2049]
    const float* __restrict__ lb,   // [4]
    float4* __restrict__ pre)       // [T*B]
{
    __shared__ float4 wlds[2048];   // [it 0..7][g 0..3][lane 0..63]
    float* wldsf = (float*)wlds;
    for (int j = threadIdx.x; j < 8192; j += 256) {
        const int it = j >> 10;
        const int g  = (j >> 8) & 3;
        wldsf[j] = lw[g * DQ + it * 256 + (j & 255)];
    }
    __syncthreads();

    const int lane = threadIdx.x & 63;
    const int wid  = blockIdx.x * 4 + (threadIdx.x >> 6);   // 0..8191
    const int row0 = wid * 16;
    const float b0 = lb[0], b1 = lb[1], b2 = lb[2], b3 = lb[3];

    const float* xb = x + (size_t)row0 * DD + lane * 4;

    // carried double-buffer: current it-chunk for the 4 active rows
    float4 xcur[4];
#pragma unroll
    for (int r = 0; r < 4; ++r)
        xcur[r] = *reinterpret_cast<const float4*>(xb + r * DD);

    for (int r0 = 0; r0 < 16; r0 += 4) {
        float a[4][4];
#pragma unroll
        for (int r = 0; r < 4; ++r)
#pragma unroll
            for (int g = 0; g < 4; ++g) a[r][g] = 0.f;

#pragma unroll
        for (int it = 0; it < 8; ++it) {
            // prefetch: next it-chunk, or next group's first chunk
            float4 xnx[4];
            const bool doload = (it < 7) || (r0 < 12);
            const float* nb = (it < 7)
                ? xb + (size_t)r0 * DD + (it + 1) * 256
                : xb + (size_t)(r0 + 4) * DD;
            if (doload) {
#pragma unroll
                for (int r = 0; r < 4; ++r)
                    xnx[r] = *reinterpret_cast<const float4*>(nb + r * DD);
            }
            const float4 w0 = wlds[(it * 4 + 0) * 64 + lane];
            const float4 w1 = wlds[(it * 4 + 1) * 64 + lane];
            const float4 w2 = wlds[(it * 4 + 2) * 64 + lane];
            const float4 w3 = wlds[(it * 4 + 3) * 64 + lane];
#pragma unroll
            for (int r = 0; r < 4; ++r) {
                const float4 xv = xcur[r];
                a[r][0] += xv.x * w0.x + xv.y * w0.y + xv.z * w0.z + xv.w * w0.w;
                a[r][1] += xv.x * w1.x + xv.y * w1.y + xv.z * w1.z + xv.w * w1.w;
                a[r][2] += xv.x * w2.x + xv.y * w2.y + xv.z * w2.z + xv.w * w2.w;
                a[r][3] += xv.x * w3.x + xv.y * w3.y + xv.z * w3.z + xv.w * w3.w;
            }
#pragma unroll
            for (int r = 0; r < 4; ++r) xcur[r] = xnx[r];
        }

        // 6-stage xor butterfly allreduce on all 16 accumulators:
        // 16 independent values per stage hide the DS latency under issue.
#pragma unroll
        for (int s = 32; s >= 1; s >>= 1) {
#pragma unroll
            for (int r = 0; r < 4; ++r) {
#pragma unroll
                for (int g = 0; g < 4; ++g)
                    a[r][g] += __shfl_xor(a[r][g], s);
            }
        }
        if (lane == 0) {
            pre[row0 + r0 + 0] = make_float4(a[0][0] + b0, a[0][1] + b1, a[0][2] + b2, a[0][3] + b3);
            pre[row0 + r0 + 1] = make_float4(a[1][0] + b0, a[1][1] + b1, a[1][2] + b2, a[1][3] + b3);
            pre[row0 + r0 + 2] = make_float4(a[2][0] + b0, a[2][1] + b1, a[2][2] + b2, a[2][3] + b3);
            pre[row0 + r0 + 3] = make_float4(a[3][0] + b0, a[3][1] + b1, a[3][2] + b2, a[3][3] + b3);
        }
    }
}

// ---- Kernel 2: sequential LSTM scan, one thread per batch element ---------
__global__ __launch_bounds__(256) void qlstm_scan(
    const float4* __restrict__ pre,   // [T*B]: x-dot + lb, per gate
    const float* __restrict__ lw,     // [4,2049] -> h-weight at col 2048
    const float* __restrict__ ew,     // enc_w [4]
    const float* __restrict__ ebv,    // enc_b [4]
    const float* __restrict__ rx,     // [4]
    const float* __restrict__ mw,     // meas_w [4]
    const float* __restrict__ mb,     // meas_b [4]
    float* __restrict__ out)          // [T*B + B + B]
{
    const int b = threadIdx.x;

    float whx[4], al[4], be[4], mww[4], mbb[4];
#pragma unroll
    for (int g = 0; g < 4; ++g) {
        whx[g] = lw[g * DQ + DD];      // h column
        al[g]  = rx[g] * ew[g];        // fold encoder*rx
        be[g]  = rx[g] * ebv[g];
        mww[g] = mw[g];
        mbb[g] = mb[g];
    }

    float h = 0.f, c = 0.f;

    float4 cur[8], nxt[8];
#pragma unroll
    for (int j = 0; j < 8; ++j) cur[j] = pre[j * BB + b];

    for (int t0 = 0; t0 < TT; t0 += 8) {
        const int tn = t0 + 8;
        if (tn < TT) {
#pragma unroll
            for (int j = 0; j < 8; ++j) nxt[j] = pre[(tn + j) * BB + b];
        }
#pragma unroll
        for (int j = 0; j < 8; ++j) {
            const float4 pc = cur[j];
            const float p0 = pc.x + h * whx[0];
            const float p1 = pc.y + h * whx[1];
            const float p2 = pc.z + h * whx[2];
            const float p3 = pc.w + h * whx[3];
            const float s0 = ftanh(al[0] * p0 + be[0]);
            const float s1 = ftanh(al[1] * p1 + be[1]);
            const float s2 = ftanh(al[2] * p2 + be[2]);
            const float s3 = ftanh(al[3] * p3 + be[3]);
            const float v0 = s0 * mww[0] + mbb[0];
            const float v1 = s1 * mww[1] + mbb[1];
            const float v2 = s2 * mww[2] + mbb[2];
            const float v3 = s3 * mww[3] + mbb[3];
            const float f  = fsig(v0);
            const float i  = fsig(v1);
            const float gg = ftanh(v2);
            const float o  = fsig(v3);
            c = f * c + i * gg;
            h = o * ftanh(c);
            out[(t0 + j) * BB + b] = h;
        }
#pragma unroll
        for (int j = 0; j < 8; ++j) cur[j] = nxt[j];
    }

    out[TT * BB + b]      = h;   // final hx
    out[TT * BB + BB + b] = c;   // final cx
}

extern "C" void kernel_launch(void* const* d_in, const int* in_sizes, int n_in,
                              void* d_out, int out_size, void* d_ws, size_t ws_size,
                              hipStream_t stream) {
    const float* x   = (const float*)d_in[0];   // [512,256,2048]
    const float* lw  = (const float*)d_in[1];   // [4,1,2049]
    const float* lb  = (const float*)d_in[2];   // [4,1]
    const float* ew  = (const float*)d_in[3];   // [4,1,1]
    const float* ebv = (const float*)d_in[4];   // [4,1]
    const float* rx  = (const float*)d_in[5];   // [4]
    const float* mw  = (const float*)d_in[6];   // [4,1,1]
    const float* mb  = (const float*)d_in[7];   // [4,1]
    float* out = (float*)d_out;
    float4* pre = (float4*)d_ws;                // 2 MiB

    qlstm_gemm<<<2048, 256, 0, stream>>>(x, lw, lb, pre);
    qlstm_scan<<<1, 256, 0, stream>>>(pre, lw, ew, ebv, rx, mw, mb, out);
}

// Round 4
// 326.084 us; speedup vs baseline: 3.3641x; 1.0756x over previous
//
#include <hip/hip_runtime.h>

#define TT 512
#define BB 256
#define DD 2048
#define DQ 2049   // D + Q (Q == 1)

typedef float f32x4 __attribute__((ext_vector_type(4)));

__device__ __forceinline__ f32x4 ntload4(const float* p) {
    return __builtin_nontemporal_load(reinterpret_cast<const f32x4*>(p));
}

// ---- fast transcendentals (v_exp_f32 / v_rcp_f32) -------------------------
__device__ __forceinline__ float fexp(float x) {
    return exp2f(x * 1.442695040888963f);      // e^x = 2^(x*log2 e)
}
__device__ __forceinline__ float frcp(float x) {
    return __builtin_amdgcn_rcpf(x);
}
__device__ __forceinline__ float ftanh(float x) {
    return 1.f - 2.f * frcp(1.f + fexp(2.f * x));
}
__device__ __forceinline__ float fsig(float x) {
    return frcp(1.f + fexp(-x));
}

// ---- Kernel 1: pre[row][g] = dot(x[row,:2048], lw[g,:2048]) + lb[g] -------
// Identical schedule to round 3 (LDS weights, 4-row groups, double-buffered
// loads) EXCEPT x is read with non-temporal loads: x has zero reuse, and the
// theory is the 3.4 TB/s wall is the per-CU L1 outstanding-miss (MSHR) limit.
// `nt` bypasses L1 allocation -> requests ride the deeper L2/TCC queues.
__global__ __launch_bounds__(256) void qlstm_gemm(
    const float* __restrict__ x,    // [T*B, 2048]
    const float* __restrict__ lw,   // [4, 2049]
    const float* __restrict__ lb,   // [4]
    f32x4* __restrict__ pre)        // [T*B]
{
    __shared__ f32x4 wlds[2048];    // [it 0..7][g 0..3][lane 0..63]
    float* wldsf = (float*)wlds;
    for (int j = threadIdx.x; j < 8192; j += 256) {
        const int it = j >> 10;
        const int g  = (j >> 8) & 3;
        wldsf[j] = lw[g * DQ + it * 256 + (j & 255)];
    }
    __syncthreads();

    const int lane = threadIdx.x & 63;
    const int wid  = blockIdx.x * 4 + (threadIdx.x >> 6);   // 0..8191
    const int row0 = wid * 16;
    const float b0 = lb[0], b1 = lb[1], b2 = lb[2], b3 = lb[3];

    const float* xb = x + (size_t)row0 * DD + lane * 4;

    f32x4 xcur[4];
#pragma unroll
    for (int r = 0; r < 4; ++r)
        xcur[r] = ntload4(xb + r * DD);

    for (int r0 = 0; r0 < 16; r0 += 4) {
        float a[4][4];
#pragma unroll
        for (int r = 0; r < 4; ++r)
#pragma unroll
            for (int g = 0; g < 4; ++g) a[r][g] = 0.f;

#pragma unroll
        for (int it = 0; it < 8; ++it) {
            f32x4 xnx[4];
            const bool doload = (it < 7) || (r0 < 12);
            const float* nb = (it < 7)
                ? xb + (size_t)r0 * DD + (it + 1) * 256
                : xb + (size_t)(r0 + 4) * DD;
            if (doload) {
#pragma unroll
                for (int r = 0; r < 4; ++r)
                    xnx[r] = ntload4(nb + r * DD);
            }
            const f32x4 w0 = wlds[(it * 4 + 0) * 64 + lane];
            const f32x4 w1 = wlds[(it * 4 + 1) * 64 + lane];
            const f32x4 w2 = wlds[(it * 4 + 2) * 64 + lane];
            const f32x4 w3 = wlds[(it * 4 + 3) * 64 + lane];
#pragma unroll
            for (int r = 0; r < 4; ++r) {
                const f32x4 xv = xcur[r];
                a[r][0] += xv[0] * w0[0] + xv[1] * w0[1] + xv[2] * w0[2] + xv[3] * w0[3];
                a[r][1] += xv[0] * w1[0] + xv[1] * w1[1] + xv[2] * w1[2] + xv[3] * w1[3];
                a[r][2] += xv[0] * w2[0] + xv[1] * w2[1] + xv[2] * w2[2] + xv[3] * w2[3];
                a[r][3] += xv[0] * w3[0] + xv[1] * w3[1] + xv[2] * w3[2] + xv[3] * w3[3];
            }
#pragma unroll
            for (int r = 0; r < 4; ++r) xcur[r] = xnx[r];
        }

#pragma unroll
        for (int s = 32; s >= 1; s >>= 1) {
#pragma unroll
            for (int r = 0; r < 4; ++r) {
#pragma unroll
                for (int g = 0; g < 4; ++g)
                    a[r][g] += __shfl_xor(a[r][g], s);
            }
        }
        if (lane == 0) {
#pragma unroll
            for (int r = 0; r < 4; ++r) {
                f32x4 o = {a[r][0] + b0, a[r][1] + b1, a[r][2] + b2, a[r][3] + b3};
                pre[row0 + r0 + r] = o;
            }
        }
    }
}

// ---- Kernel 2: sequential LSTM scan (UNCHANGED control) -------------------
__global__ __launch_bounds__(256) void qlstm_scan(
    const float4* __restrict__ pre,   // [T*B]: x-dot + lb, per gate
    const float* __restrict__ lw,     // [4,2049] -> h-weight at col 2048
    const float* __restrict__ ew,     // enc_w [4]
    const float* __restrict__ ebv,    // enc_b [4]
    const float* __restrict__ rx,     // [4]
    const float* __restrict__ mw,     // meas_w [4]
    const float* __restrict__ mb,     // meas_b [4]
    float* __restrict__ out)          // [T*B + B + B]
{
    const int b = threadIdx.x;

    float whx[4], al[4], be[4], mww[4], mbb[4];
#pragma unroll
    for (int g = 0; g < 4; ++g) {
        whx[g] = lw[g * DQ + DD];      // h column
        al[g]  = rx[g] * ew[g];        // fold encoder*rx
        be[g]  = rx[g] * ebv[g];
        mww[g] = mw[g];
        mbb[g] = mb[g];
    }

    float h = 0.f, c = 0.f;

    float4 cur[8], nxt[8];
#pragma unroll
    for (int j = 0; j < 8; ++j) cur[j] = pre[j * BB + b];

    for (int t0 = 0; t0 < TT; t0 += 8) {
        const int tn = t0 + 8;
        if (tn < TT) {
#pragma unroll
            for (int j = 0; j < 8; ++j) nxt[j] = pre[(tn + j) * BB + b];
        }
#pragma unroll
        for (int j = 0; j < 8; ++j) {
            const float4 pc = cur[j];
            const float p0 = pc.x + h * whx[0];
            const float p1 = pc.y + h * whx[1];
            const float p2 = pc.z + h * whx[2];
            const float p3 = pc.w + h * whx[3];
            const float s0 = ftanh(al[0] * p0 + be[0]);
            const float s1 = ftanh(al[1] * p1 + be[1]);
            const float s2 = ftanh(al[2] * p2 + be[2]);
            const float s3 = ftanh(al[3] * p3 + be[3]);
            const float v0 = s0 * mww[0] + mbb[0];
            const float v1 = s1 * mww[1] + mbb[1];
            const float v2 = s2 * mww[2] + mbb[2];
            const float v3 = s3 * mww[3] + mbb[3];
            const float f  = fsig(v0);
            const float i  = fsig(v1);
            const float gg = ftanh(v2);
            const float o  = fsig(v3);
            c = f * c + i * gg;
            h = o * ftanh(c);
            out[(t0 + j) * BB + b] = h;
        }
#pragma unroll
        for (int j = 0; j < 8; ++j) cur[j] = nxt[j];
    }

    out[TT * BB + b]      = h;   // final hx
    out[TT * BB + BB + b] = c;   // final cx
}

extern "C" void kernel_launch(void* const* d_in, const int* in_sizes, int n_in,
                              void* d_out, int out_size, void* d_ws, size_t ws_size,
                              hipStream_t stream) {
    const float* x   = (const float*)d_in[0];   // [512,256,2048]
    const float* lw  = (const float*)d_in[1];   // [4,1,2049]
    const float* lb  = (const float*)d_in[2];   // [4,1]
    const float* ew  = (const float*)d_in[3];   // [4,1,1]
    const float* ebv = (const float*)d_in[4];   // [4,1]
    const float* rx  = (const float*)d_in[5];   // [4]
    const float* mw  = (const float*)d_in[6];   // [4,1,1]
    const float* mb  = (const float*)d_in[7];   // [4,1]
    float* out = (float*)d_out;

    qlstm_gemm<<<2048, 256, 0, stream>>>(x, lw, lb, (f32x4*)d_ws);
    qlstm_scan<<<1, 256, 0, stream>>>((const float4*)d_ws, lw, ew, ebv, rx, mw, mb, out);
}

// Round 5
// 311.606 us; speedup vs baseline: 3.5204x; 1.0465x over previous
//
#include <hip/hip_runtime.h>

#define TT 512
#define BB 256
#define DD 2048
#define DQ 2049                   // D + Q (Q == 1)
#define CH_T 128                  // timesteps per chunk (4 chunks)
#define CH_ROWS (CH_T * BB)       // 32768 rows per chunk
#define CH_WAVES (CH_ROWS / 16)   // 2048 waves per chunk
#define CH_BLOCKS (CH_WAVES / 4)  // 512 blocks per chunk

typedef float f32x4 __attribute__((ext_vector_type(4)));

__device__ __forceinline__ f32x4 ntload4(const float* p) {
    return __builtin_nontemporal_load(reinterpret_cast<const f32x4*>(p));
}
__device__ __forceinline__ float frcp(float x) { return __builtin_amdgcn_rcpf(x); }
__device__ __forceinline__ float ftanh(float x) {
    const float e = exp2f(x * 2.8853900817779268f);   // 2^(2x*log2e) = e^(2x)
    return 1.f - 2.f * frcp(1.f + e);
}
__device__ __forceinline__ float fsig(float x) {
    const float e = exp2f(-x * 1.4426950408889634f);  // e^-x
    return frcp(1.f + e);
}

// ---- GEMM part: one wave = 16 rows; epilogue folds rx*enc (al, be) --------
// pre'[row][g] = al[g] * (dot(x,lw[g]) + lb[g]) + be[g]
__device__ __forceinline__ void gemm_part(
    const float* __restrict__ x, const float* __restrict__ lw,
    const float* __restrict__ lb, const float* __restrict__ ew,
    const float* __restrict__ ebv, const float* __restrict__ rx,
    f32x4* __restrict__ pre, int wave_base, int block_off)
{
    __shared__ f32x4 wlds[2048];    // [it 0..7][g 0..3][lane 0..63]
    float* wldsf = (float*)wlds;
    for (int j = threadIdx.x; j < 8192; j += 256) {
        const int it = j >> 10;
        const int g  = (j >> 8) & 3;
        wldsf[j] = lw[g * DQ + it * 256 + (j & 255)];
    }
    __syncthreads();

    const int lane = threadIdx.x & 63;
    const int wid  = wave_base + (blockIdx.x - block_off) * 4 + (threadIdx.x >> 6);
    const int row0 = wid * 16;

    float alv[4], bev[4], lbv[4];
#pragma unroll
    for (int g = 0; g < 4; ++g) {
        alv[g] = rx[g] * ew[g];
        bev[g] = rx[g] * ebv[g];
        lbv[g] = lb[g];
    }

    const float* xb = x + (size_t)row0 * DD + lane * 4;

    f32x4 xcur[4];
#pragma unroll
    for (int r = 0; r < 4; ++r) xcur[r] = ntload4(xb + r * DD);

    for (int r0 = 0; r0 < 16; r0 += 4) {
        float a[4][4];
#pragma unroll
        for (int r = 0; r < 4; ++r)
#pragma unroll
            for (int g = 0; g < 4; ++g) a[r][g] = 0.f;

#pragma unroll
        for (int it = 0; it < 8; ++it) {
            f32x4 xnx[4];
            const bool doload = (it < 7) || (r0 < 12);
            const float* nb = (it < 7)
                ? xb + (size_t)r0 * DD + (it + 1) * 256
                : xb + (size_t)(r0 + 4) * DD;
            if (doload) {
#pragma unroll
                for (int r = 0; r < 4; ++r) xnx[r] = ntload4(nb + r * DD);
            }
            const f32x4 w0 = wlds[(it * 4 + 0) * 64 + lane];
            const f32x4 w1 = wlds[(it * 4 + 1) * 64 + lane];
            const f32x4 w2 = wlds[(it * 4 + 2) * 64 + lane];
            const f32x4 w3 = wlds[(it * 4 + 3) * 64 + lane];
#pragma unroll
            for (int r = 0; r < 4; ++r) {
                const f32x4 xv = xcur[r];
                a[r][0] += xv[0] * w0[0] + xv[1] * w0[1] + xv[2] * w0[2] + xv[3] * w0[3];
                a[r][1] += xv[0] * w1[0] + xv[1] * w1[1] + xv[2] * w1[2] + xv[3] * w1[3];
                a[r][2] += xv[0] * w2[0] + xv[1] * w2[1] + xv[2] * w2[2] + xv[3] * w2[3];
                a[r][3] += xv[0] * w3[0] + xv[1] * w3[1] + xv[2] * w3[2] + xv[3] * w3[3];
            }
#pragma unroll
            for (int r = 0; r < 4; ++r) xcur[r] = xnx[r];
        }

#pragma unroll
        for (int s = 32; s >= 1; s >>= 1) {
#pragma unroll
            for (int r = 0; r < 4; ++r)
#pragma unroll
                for (int g = 0; g < 4; ++g)
                    a[r][g] += __shfl_xor(a[r][g], s);
        }
        if (lane == 0) {
#pragma unroll
            for (int r = 0; r < 4; ++r) {
                f32x4 o = {alv[0] * (a[r][0] + lbv[0]) + bev[0],
                           alv[1] * (a[r][1] + lbv[1]) + bev[1],
                           alv[2] * (a[r][2] + lbv[2]) + bev[2],
                           alv[3] * (a[r][3] + lbv[3]) + bev[3]};
                pre[row0 + r0 + r] = o;
            }
        }
    }
}

// ---- scan part: CH_T steps, one thread per batch element ------------------
__device__ __forceinline__ void scan_part(
    const f32x4* __restrict__ pre, const float* __restrict__ lw,
    const float* __restrict__ ew, const float* __restrict__ ebv,
    const float* __restrict__ rx, const float* __restrict__ mw,
    const float* __restrict__ mb, float* __restrict__ out,
    float* __restrict__ hc, int t0)
{
    const int b = threadIdx.x;

    float aw[4], mww[4], mbb[4];
#pragma unroll
    for (int g = 0; g < 4; ++g) {
        aw[g]  = rx[g] * ew[g] * lw[g * DQ + DD];   // al[g] * whx[g]
        mww[g] = mw[g];
        mbb[g] = mb[g];
    }

    float h, c;
    if (t0 == 0) { h = 0.f; c = 0.f; }
    else         { h = hc[b]; c = hc[BB + b]; }

    f32x4 cur[8], nxt[8];
#pragma unroll
    for (int j = 0; j < 8; ++j) cur[j] = pre[(t0 + j) * BB + b];

    for (int tt = t0; tt < t0 + CH_T; tt += 8) {
        const int tn = tt + 8;
        if (tn < t0 + CH_T) {
#pragma unroll
            for (int j = 0; j < 8; ++j) nxt[j] = pre[(tn + j) * BB + b];
        }
#pragma unroll
        for (int j = 0; j < 8; ++j) {
            const f32x4 pc = cur[j];
            const float s0 = ftanh(fmaf(h, aw[0], pc[0]));
            const float s1 = ftanh(fmaf(h, aw[1], pc[1]));
            const float s2 = ftanh(fmaf(h, aw[2], pc[2]));
            const float s3 = ftanh(fmaf(h, aw[3], pc[3]));
            const float f  = fsig(fmaf(s0, mww[0], mbb[0]));
            const float i  = fsig(fmaf(s1, mww[1], mbb[1]));
            const float gg = ftanh(fmaf(s2, mww[2], mbb[2]));
            const float o  = fsig(fmaf(s3, mww[3], mbb[3]));
            c = f * c + i * gg;
            h = o * ftanh(c);
            out[(tt + j) * BB + b] = h;
        }
#pragma unroll
        for (int j = 0; j < 8; ++j) cur[j] = nxt[j];
    }

    hc[b]      = h;
    hc[BB + b] = c;
    if (t0 + CH_T == TT) {
        out[TT * BB + b]      = h;
        out[TT * BB + BB + b] = c;
    }
}

// ---- kernels --------------------------------------------------------------
__global__ __launch_bounds__(256) void k_gemm0(
    const float* __restrict__ x, const float* __restrict__ lw,
    const float* __restrict__ lb, const float* __restrict__ ew,
    const float* __restrict__ ebv, const float* __restrict__ rx,
    f32x4* __restrict__ pre)
{
    gemm_part(x, lw, lb, ew, ebv, rx, pre, 0, 0);
}

// block 0: scan chunk [scan_t0, scan_t0+CH_T) over pre written by PREVIOUS
// launch (kernel-boundary dependency — fully coherent). blocks >= 1: gemm of
// the NEXT chunk (disjoint pre rows).
__global__ __launch_bounds__(256) void k_mix(
    const float* __restrict__ x, const float* __restrict__ lw,
    const float* __restrict__ lb, const float* __restrict__ ew,
    const float* __restrict__ ebv, const float* __restrict__ rx,
    const float* __restrict__ mw, const float* __restrict__ mb,
    f32x4* __restrict__ pre, float* __restrict__ out,
    float* __restrict__ hc, int scan_t0, int wave_base)
{
    if (blockIdx.x == 0)
        scan_part(pre, lw, ew, ebv, rx, mw, mb, out, hc, scan_t0);
    else
        gemm_part(x, lw, lb, ew, ebv, rx, pre, wave_base, 1);
}

extern "C" void kernel_launch(void* const* d_in, const int* in_sizes, int n_in,
                              void* d_out, int out_size, void* d_ws, size_t ws_size,
                              hipStream_t stream) {
    const float* x   = (const float*)d_in[0];   // [512,256,2048]
    const float* lw  = (const float*)d_in[1];   // [4,1,2049]
    const float* lb  = (const float*)d_in[2];   // [4,1]
    const float* ew  = (const float*)d_in[3];   // [4,1,1]
    const float* ebv = (const float*)d_in[4];   // [4,1]
    const float* rx  = (const float*)d_in[5];   // [4]
    const float* mw  = (const float*)d_in[6];   // [4,1,1]
    const float* mb  = (const float*)d_in[7];   // [4,1]
    float* out = (float*)d_out;

    f32x4* pre = (f32x4*)d_ws;                              // 2 MiB
    float* hc  = (float*)((char*)d_ws + (size_t)TT * BB * 16);  // 2 KB

    k_gemm0<<<CH_BLOCKS, 256, 0, stream>>>(x, lw, lb, ew, ebv, rx, pre);
    k_mix<<<CH_BLOCKS + 1, 256, 0, stream>>>(x, lw, lb, ew, ebv, rx, mw, mb,
                                             pre, out, hc, 0, CH_WAVES);
    k_mix<<<CH_BLOCKS + 1, 256, 0, stream>>>(x, lw, lb, ew, ebv, rx, mw, mb,
                                             pre, out, hc, CH_T, 2 * CH_WAVES);
    k_mix<<<CH_BLOCKS + 1, 256, 0, stream>>>(x, lw, lb, ew, ebv, rx, mw, mb,
                                             pre, out, hc, 2 * CH_T, 3 * CH_WAVES);
    k_mix<<<1, 256, 0, stream>>>(x, lw, lb, ew, ebv, rx, mw, mb,
                                 pre, out, hc, 3 * CH_T, 0);
}

// Round 6
// 273.841 us; speedup vs baseline: 4.0059x; 1.1379x over previous
//
#include <hip/hip_runtime.h>

#define TT 512
#define BB 256
#define DD 2048
#define DQ 2049                   // D + Q (Q == 1)
#define CH_T 128                  // timesteps per chunk (4 chunks)
#define CH_ROWS (CH_T * BB)       // 32768 rows per chunk
#define CH_WAVES (CH_ROWS / 16)   // 2048 waves per chunk
#define CH_BLOCKS (CH_WAVES / 4)  // 512 blocks per chunk

typedef float f32x4 __attribute__((ext_vector_type(4)));

// system-scope non-temporal load: bypass L1 and L2 allocation (read-once x)
__device__ __forceinline__ void ldg_nt(f32x4& d, const float* p) {
    asm volatile("global_load_dwordx4 %0, %1, off sc0 sc1 nt"
                 : "=v"(d) : "v"(p));
}
// counted waits; the waited regs are read-write operands so all consumers are
// data-ordered AFTER the wait (rule-18 hoist hazard avoided by dataflow).
__device__ __forceinline__ void wait_vm4(f32x4& a, f32x4& b, f32x4& c, f32x4& d) {
    asm volatile("s_waitcnt vmcnt(4)" : "+v"(a), "+v"(b), "+v"(c), "+v"(d));
}
__device__ __forceinline__ void wait_vm0(f32x4& a, f32x4& b, f32x4& c, f32x4& d) {
    asm volatile("s_waitcnt vmcnt(0)" : "+v"(a), "+v"(b), "+v"(c), "+v"(d));
}

__device__ __forceinline__ float frcp(float x) { return __builtin_amdgcn_rcpf(x); }
__device__ __forceinline__ float ftanh(float x) {
    const float e = exp2f(x * 2.8853900817779268f);   // e^(2x)
    return 1.f - 2.f * frcp(1.f + e);
}
__device__ __forceinline__ float fsig(float x) {
    const float e = exp2f(-x * 1.4426950408889634f);  // e^-x
    return frcp(1.f + e);
}

// ---- GEMM part: one wave = 16 rows; epilogue folds rx*enc (al, be) --------
// pre'[row][g] = al[g] * (dot(x,lw[g]) + lb[g]) + be[g]
__device__ __forceinline__ void gemm_part(
    const float* __restrict__ x, const float* __restrict__ lw,
    const float* __restrict__ lb, const float* __restrict__ ew,
    const float* __restrict__ ebv, const float* __restrict__ rx,
    f32x4* __restrict__ pre, int wave_base, int block_off)
{
    __shared__ f32x4 wlds[2048];    // [it 0..7][g 0..3][lane 0..63]
    float* wldsf = (float*)wlds;
    for (int j = threadIdx.x; j < 8192; j += 256) {
        const int it = j >> 10;
        const int g  = (j >> 8) & 3;
        wldsf[j] = lw[g * DQ + it * 256 + (j & 255)];
    }
    __syncthreads();

    const int lane = threadIdx.x & 63;
    const int wid  = wave_base + (blockIdx.x - block_off) * 4 + (threadIdx.x >> 6);
    const int row0 = wid * 16;

    float alv[4], bev[4], lbv[4];
#pragma unroll
    for (int g = 0; g < 4; ++g) {
        alv[g] = rx[g] * ew[g];
        bev[g] = rx[g] * ebv[g];
        lbv[g] = lb[g];
    }

    const float* xb = x + (size_t)row0 * DD + lane * 4;

    f32x4 xcur[4], xnx[4];
#pragma unroll
    for (int r = 0; r < 4; ++r) ldg_nt(xcur[r], xb + r * DD);   // prime: 4 in flight

#pragma unroll
    for (int r0 = 0; r0 < 16; r0 += 4) {
        float a[4][4];
#pragma unroll
        for (int r = 0; r < 4; ++r)
#pragma unroll
            for (int g = 0; g < 4; ++g) a[r][g] = 0.f;

#pragma unroll
        for (int it = 0; it < 8; ++it) {
            const bool last = (it == 7) && (r0 == 12);
            if (!last) {
                const float* nb = (it < 7)
                    ? xb + (size_t)r0 * DD + (it + 1) * 256
                    : xb + (size_t)(r0 + 4) * DD;
#pragma unroll
                for (int r = 0; r < 4; ++r) ldg_nt(xnx[r], nb + r * DD);
            }
            // drain everything older than the 4 just-issued loads
            // (covers xcur's batch and any epilogue stores)
            if (last) wait_vm0(xcur[0], xcur[1], xcur[2], xcur[3]);
            else      wait_vm4(xcur[0], xcur[1], xcur[2], xcur[3]);

            const f32x4 w0 = wlds[(it * 4 + 0) * 64 + lane];
            const f32x4 w1 = wlds[(it * 4 + 1) * 64 + lane];
            const f32x4 w2 = wlds[(it * 4 + 2) * 64 + lane];
            const f32x4 w3 = wlds[(it * 4 + 3) * 64 + lane];
#pragma unroll
            for (int r = 0; r < 4; ++r) {
                const f32x4 xv = xcur[r];
                a[r][0] += xv[0] * w0[0] + xv[1] * w0[1] + xv[2] * w0[2] + xv[3] * w0[3];
                a[r][1] += xv[0] * w1[0] + xv[1] * w1[1] + xv[2] * w1[2] + xv[3] * w1[3];
                a[r][2] += xv[0] * w2[0] + xv[1] * w2[1] + xv[2] * w2[2] + xv[3] * w2[3];
                a[r][3] += xv[0] * w3[0] + xv[1] * w3[1] + xv[2] * w3[2] + xv[3] * w3[3];
            }
#pragma unroll
            for (int r = 0; r < 4; ++r) xcur[r] = xnx[r];       // SSA rename (unrolled)
        }

#pragma unroll
        for (int s = 32; s >= 1; s >>= 1) {
#pragma unroll
            for (int r = 0; r < 4; ++r)
#pragma unroll
                for (int g = 0; g < 4; ++g)
                    a[r][g] += __shfl_xor(a[r][g], s);
        }
        if (lane == 0) {
#pragma unroll
            for (int r = 0; r < 4; ++r) {
                f32x4 o = {alv[0] * (a[r][0] + lbv[0]) + bev[0],
                           alv[1] * (a[r][1] + lbv[1]) + bev[1],
                           alv[2] * (a[r][2] + lbv[2]) + bev[2],
                           alv[3] * (a[r][3] + lbv[3]) + bev[3]};
                pre[row0 + r0 + r] = o;
            }
        }
    }
}

// ---- scan part: CH_T steps, one thread per batch element ------------------
__device__ __forceinline__ void scan_part(
    const f32x4* __restrict__ pre, const float* __restrict__ lw,
    const float* __restrict__ ew, const float* __restrict__ ebv,
    const float* __restrict__ rx, const float* __restrict__ mw,
    const float* __restrict__ mb, float* __restrict__ out,
    float* __restrict__ hc, int t0)
{
    const int b = threadIdx.x;

    float aw[4], mww[4], mbb[4];
#pragma unroll
    for (int g = 0; g < 4; ++g) {
        aw[g]  = rx[g] * ew[g] * lw[g * DQ + DD];   // al[g] * whx[g]
        mww[g] = mw[g];
        mbb[g] = mb[g];
    }

    float h, c;
    if (t0 == 0) { h = 0.f; c = 0.f; }
    else         { h = hc[b]; c = hc[BB + b]; }

    f32x4 cur[8], nxt[8];
#pragma unroll
    for (int j = 0; j < 8; ++j) cur[j] = pre[(t0 + j) * BB + b];

    for (int tt = t0; tt < t0 + CH_T; tt += 8) {
        const int tn = tt + 8;
        if (tn < t0 + CH_T) {
#pragma unroll
            for (int j = 0; j < 8; ++j) nxt[j] = pre[(tn + j) * BB + b];
        }
#pragma unroll
        for (int j = 0; j < 8; ++j) {
            const f32x4 pc = cur[j];
            const float s0 = ftanh(fmaf(h, aw[0], pc[0]));
            const float s1 = ftanh(fmaf(h, aw[1], pc[1]));
            const float s2 = ftanh(fmaf(h, aw[2], pc[2]));
            const float s3 = ftanh(fmaf(h, aw[3], pc[3]));
            const float f  = fsig(fmaf(s0, mww[0], mbb[0]));
            const float i  = fsig(fmaf(s1, mww[1], mbb[1]));
            const float gg = ftanh(fmaf(s2, mww[2], mbb[2]));
            const float o  = fsig(fmaf(s3, mww[3], mbb[3]));
            c = f * c + i * gg;
            h = o * ftanh(c);
            out[(tt + j) * BB + b] = h;
        }
#pragma unroll
        for (int j = 0; j < 8; ++j) cur[j] = nxt[j];
    }

    hc[b]      = h;
    hc[BB + b] = c;
    if (t0 + CH_T == TT) {
        out[TT * BB + b]      = h;
        out[TT * BB + BB + b] = c;
    }
}

// ---- kernels --------------------------------------------------------------
__global__ __launch_bounds__(256) void k_gemm0(
    const float* __restrict__ x, const float* __restrict__ lw,
    const float* __restrict__ lb, const float* __restrict__ ew,
    const float* __restrict__ ebv, const float* __restrict__ rx,
    f32x4* __restrict__ pre)
{
    gemm_part(x, lw, lb, ew, ebv, rx, pre, 0, 0);
}

// block 0: scan chunk [scan_t0, scan_t0+CH_T) over pre written by PREVIOUS
// launch (kernel-boundary dependency — fully coherent). blocks >= 1: gemm of
// the NEXT chunk (disjoint pre rows).
__global__ __launch_bounds__(256) void k_mix(
    const float* __restrict__ x, const float* __restrict__ lw,
    const float* __restrict__ lb, const float* __restrict__ ew,
    const float* __restrict__ ebv, const float* __restrict__ rx,
    const float* __restrict__ mw, const float* __restrict__ mb,
    f32x4* __restrict__ pre, float* __restrict__ out,
    float* __restrict__ hc, int scan_t0, int wave_base)
{
    if (blockIdx.x == 0)
        scan_part(pre, lw, ew, ebv, rx, mw, mb, out, hc, scan_t0);
    else
        gemm_part(x, lw, lb, ew, ebv, rx, pre, wave_base, 1);
}

extern "C" void kernel_launch(void* const* d_in, const int* in_sizes, int n_in,
                              void* d_out, int out_size, void* d_ws, size_t ws_size,
                              hipStream_t stream) {
    const float* x   = (const float*)d_in[0];   // [512,256,2048]
    const float* lw  = (const float*)d_in[1];   // [4,1,2049]
    const float* lb  = (const float*)d_in[2];   // [4,1]
    const float* ew  = (const float*)d_in[3];   // [4,1,1]
    const float* ebv = (const float*)d_in[4];   // [4,1]
    const float* rx  = (const float*)d_in[5];   // [4]
    const float* mw  = (const float*)d_in[6];   // [4,1,1]
    const float* mb  = (const float*)d_in[7];   // [4,1]
    float* out = (float*)d_out;

    f32x4* pre = (f32x4*)d_ws;                              // 2 MiB
    float* hc  = (float*)((char*)d_ws + (size_t)TT * BB * 16);  // 2 KB

    k_gemm0<<<CH_BLOCKS, 256, 0, stream>>>(x, lw, lb, ew, ebv, rx, pre);
    k_mix<<<CH_BLOCKS + 1, 256, 0, stream>>>(x, lw, lb, ew, ebv, rx, mw, mb,
                                             pre, out, hc, 0, CH_WAVES);
    k_mix<<<CH_BLOCKS + 1, 256, 0, stream>>>(x, lw, lb, ew, ebv, rx, mw, mb,
                                             pre, out, hc, CH_T, 2 * CH_WAVES);
    k_mix<<<CH_BLOCKS + 1, 256, 0, stream>>>(x, lw, lb, ew, ebv, rx, mw, mb,
                                             pre, out, hc, 2 * CH_T, 3 * CH_WAVES);
    k_mix<<<1, 256, 0, stream>>>(x, lw, lb, ew, ebv, rx, mw, mb,
                                 pre, out, hc, 3 * CH_T, 0);
}

// Round 7
// 239.549 us; speedup vs baseline: 4.5794x; 1.1432x over previous
//
#include <hip/hip_runtime.h>

#define TT 512
#define BB 256
#define DD 2048
#define DQ 2049                   // D + Q (Q == 1)
#define CH_T 128                  // timesteps per chunk (4 chunks)
#define CH_ROWS (CH_T * BB)       // 32768 rows per chunk
#define RPW 8                     // rows per wave
#define CH_WAVES (CH_ROWS / RPW)  // 4096 waves per chunk
#define CH_BLOCKS (CH_WAVES / 4)  // 1024 blocks per chunk

typedef float f32x4 __attribute__((ext_vector_type(4)));

// system-scope non-temporal load: bypass L1 and L2 allocation (read-once x)
__device__ __forceinline__ void ldg_nt(f32x4& d, const float* p) {
    asm volatile("global_load_dwordx4 %0, %1, off sc0 sc1 nt"
                 : "=v"(d) : "v"(p));
}
// counted waits; waited regs are read-write operands so consumers are
// data-ordered AFTER the wait (rule-18 hoist hazard avoided by dataflow).
__device__ __forceinline__ void wait_vm8(f32x4& a, f32x4& b, f32x4& c, f32x4& d) {
    asm volatile("s_waitcnt vmcnt(8)" : "+v"(a), "+v"(b), "+v"(c), "+v"(d));
}
__device__ __forceinline__ void wait_vm4(f32x4& a, f32x4& b, f32x4& c, f32x4& d) {
    asm volatile("s_waitcnt vmcnt(4)" : "+v"(a), "+v"(b), "+v"(c), "+v"(d));
}
__device__ __forceinline__ void wait_vm0(f32x4& a, f32x4& b, f32x4& c, f32x4& d) {
    asm volatile("s_waitcnt vmcnt(0)" : "+v"(a), "+v"(b), "+v"(c), "+v"(d));
}

__device__ __forceinline__ float frcp(float x) { return __builtin_amdgcn_rcpf(x); }
__device__ __forceinline__ float ftanh(float x) {
    const float e = exp2f(x * 2.8853900817779268f);   // e^(2x)
    return 1.f - 2.f * frcp(1.f + e);
}
__device__ __forceinline__ float fsig(float x) {
    const float e = exp2f(-x * 1.4426950408889634f);  // e^-x
    return frcp(1.f + e);
}

// ---- GEMM part: one wave = 8 rows, 3-deep (12-load) pipeline --------------
// pre'[row][g] = al[g] * (dot(x,lw[g]) + lb[g]) + be[g]
__device__ __forceinline__ void gemm_part(
    const float* __restrict__ x, const float* __restrict__ lw,
    const float* __restrict__ lb, const float* __restrict__ ew,
    const float* __restrict__ ebv, const float* __restrict__ rx,
    f32x4* __restrict__ pre, int wave_base, int block_off)
{
    __shared__ f32x4 wlds[2048];    // [it 0..7][g 0..3][lane 0..63]
    float* wldsf = (float*)wlds;
    for (int j = threadIdx.x; j < 8192; j += 256) {
        const int it = j >> 10;
        const int g  = (j >> 8) & 3;
        wldsf[j] = lw[g * DQ + it * 256 + (j & 255)];
    }
    __syncthreads();

    const int lane = threadIdx.x & 63;
    const int wid  = wave_base + (blockIdx.x - block_off) * 4 + (threadIdx.x >> 6);
    const int row0 = wid * RPW;

    float alv[4], bev[4], lbv[4];
#pragma unroll
    for (int g = 0; g < 4; ++g) {
        alv[g] = rx[g] * ew[g];
        bev[g] = rx[g] * ebv[g];
        lbv[g] = lb[g];
    }

    const float* xbp = x + (size_t)row0 * DD + lane * 4;

    // batch s (s = grp*8 + it, grp in {0,1}) loads rows grp*4..grp*4+3,
    // columns it*256..+255. 3 rotating buffers, 12 loads in flight.
    f32x4 xbuf[3][4];
#pragma unroll
    for (int r = 0; r < 4; ++r) ldg_nt(xbuf[0][r], xbp + (size_t)r * DD);
#pragma unroll
    for (int r = 0; r < 4; ++r) ldg_nt(xbuf[1][r], xbp + (size_t)r * DD + 256);

    float a[4][4];
#pragma unroll
    for (int s = 0; s < 16; ++s) {
        const int grp = s >> 3, it = s & 7;
        if (it == 0) {
#pragma unroll
            for (int r = 0; r < 4; ++r)
#pragma unroll
                for (int q = 0; q < 4; ++q) a[r][q] = 0.f;
        }
        if (s + 2 < 16) {
            const int s2 = s + 2, g2 = s2 >> 3, it2 = s2 & 7;
#pragma unroll
            for (int r = 0; r < 4; ++r)
                ldg_nt(xbuf[s2 % 3][r],
                       xbp + (size_t)(g2 * 4 + r) * DD + it2 * 256);
        }
        // steady state: 12 loads in flight; wait until batch s complete.
        if (s < 14)
            wait_vm8(xbuf[s % 3][0], xbuf[s % 3][1], xbuf[s % 3][2], xbuf[s % 3][3]);
        else if (s == 14)
            wait_vm4(xbuf[s % 3][0], xbuf[s % 3][1], xbuf[s % 3][2], xbuf[s % 3][3]);
        else
            wait_vm0(xbuf[s % 3][0], xbuf[s % 3][1], xbuf[s % 3][2], xbuf[s % 3][3]);

        const f32x4 w0 = wlds[(it * 4 + 0) * 64 + lane];
        const f32x4 w1 = wlds[(it * 4 + 1) * 64 + lane];
        const f32x4 w2 = wlds[(it * 4 + 2) * 64 + lane];
        const f32x4 w3 = wlds[(it * 4 + 3) * 64 + lane];
#pragma unroll
        for (int r = 0; r < 4; ++r) {
            const f32x4 xv = xbuf[s % 3][r];
            a[r][0] += xv[0] * w0[0] + xv[1] * w0[1] + xv[2] * w0[2] + xv[3] * w0[3];
            a[r][1] += xv[0] * w1[0] + xv[1] * w1[1] + xv[2] * w1[2] + xv[3] * w1[3];
            a[r][2] += xv[0] * w2[0] + xv[1] * w2[1] + xv[2] * w2[2] + xv[3] * w2[3];
            a[r][3] += xv[0] * w3[0] + xv[1] * w3[1] + xv[2] * w3[2] + xv[3] * w3[3];
        }

        if (it == 7) {
#pragma unroll
            for (int st = 32; st >= 1; st >>= 1) {
#pragma unroll
                for (int r = 0; r < 4; ++r)
#pragma unroll
                    for (int q = 0; q < 4; ++q)
                        a[r][q] += __shfl_xor(a[r][q], st);
            }
            if (lane == 0) {
#pragma unroll
                for (int r = 0; r < 4; ++r) {
                    f32x4 o = {alv[0] * (a[r][0] + lbv[0]) + bev[0],
                               alv[1] * (a[r][1] + lbv[1]) + bev[1],
                               alv[2] * (a[r][2] + lbv[2]) + bev[2],
                               alv[3] * (a[r][3] + lbv[3]) + bev[3]};
                    pre[row0 + grp * 4 + r] = o;
                }
            }
        }
    }
}

// ---- scan part: CH_T steps, one thread per batch element ------------------
__device__ __forceinline__ void scan_part(
    const f32x4* __restrict__ pre, const float* __restrict__ lw,
    const float* __restrict__ ew, const float* __restrict__ ebv,
    const float* __restrict__ rx, const float* __restrict__ mw,
    const float* __restrict__ mb, float* __restrict__ out,
    float* __restrict__ hc, int t0)
{
    const int b = threadIdx.x;

    float aw[4], mww[4], mbb[4];
#pragma unroll
    for (int g = 0; g < 4; ++g) {
        aw[g]  = rx[g] * ew[g] * lw[g * DQ + DD];   // al[g] * whx[g]
        mww[g] = mw[g];
        mbb[g] = mb[g];
    }

    float h, c;
    if (t0 == 0) { h = 0.f; c = 0.f; }
    else         { h = hc[b]; c = hc[BB + b]; }

    f32x4 cur[8], nxt[8];
#pragma unroll
    for (int j = 0; j < 8; ++j) cur[j] = pre[(t0 + j) * BB + b];

    for (int tt = t0; tt < t0 + CH_T; tt += 8) {
        const int tn = tt + 8;
        if (tn < t0 + CH_T) {
#pragma unroll
            for (int j = 0; j < 8; ++j) nxt[j] = pre[(tn + j) * BB + b];
        }
#pragma unroll
        for (int j = 0; j < 8; ++j) {
            const f32x4 pc = cur[j];
            const float s0 = ftanh(fmaf(h, aw[0], pc[0]));
            const float s1 = ftanh(fmaf(h, aw[1], pc[1]));
            const float s2 = ftanh(fmaf(h, aw[2], pc[2]));
            const float s3 = ftanh(fmaf(h, aw[3], pc[3]));
            const float f  = fsig(fmaf(s0, mww[0], mbb[0]));
            const float i  = fsig(fmaf(s1, mww[1], mbb[1]));
            const float gg = ftanh(fmaf(s2, mww[2], mbb[2]));
            const float o  = fsig(fmaf(s3, mww[3], mbb[3]));
            c = f * c + i * gg;
            h = o * ftanh(c);
            out[(tt + j) * BB + b] = h;
        }
#pragma unroll
        for (int j = 0; j < 8; ++j) cur[j] = nxt[j];
    }

    hc[b]      = h;
    hc[BB + b] = c;
    if (t0 + CH_T == TT) {
        out[TT * BB + b]      = h;
        out[TT * BB + BB + b] = c;
    }
}

// ---- kernels --------------------------------------------------------------
__global__ __launch_bounds__(256) void k_gemm0(
    const float* __restrict__ x, const float* __restrict__ lw,
    const float* __restrict__ lb, const float* __restrict__ ew,
    const float* __restrict__ ebv, const float* __restrict__ rx,
    f32x4* __restrict__ pre)
{
    gemm_part(x, lw, lb, ew, ebv, rx, pre, 0, 0);
}

// block 0: scan chunk [scan_t0, scan_t0+CH_T) over pre written by PREVIOUS
// launch (kernel-boundary dependency — fully coherent). blocks >= 1: gemm of
// the NEXT chunk (disjoint pre rows).
__global__ __launch_bounds__(256) void k_mix(
    const float* __restrict__ x, const float* __restrict__ lw,
    const float* __restrict__ lb, const float* __restrict__ ew,
    const float* __restrict__ ebv, const float* __restrict__ rx,
    const float* __restrict__ mw, const float* __restrict__ mb,
    f32x4* __restrict__ pre, float* __restrict__ out,
    float* __restrict__ hc, int scan_t0, int wave_base)
{
    if (blockIdx.x == 0)
        scan_part(pre, lw, ew, ebv, rx, mw, mb, out, hc, scan_t0);
    else
        gemm_part(x, lw, lb, ew, ebv, rx, pre, wave_base, 1);
}

extern "C" void kernel_launch(void* const* d_in, const int* in_sizes, int n_in,
                              void* d_out, int out_size, void* d_ws, size_t ws_size,
                              hipStream_t stream) {
    const float* x   = (const float*)d_in[0];   // [512,256,2048]
    const float* lw  = (const float*)d_in[1];   // [4,1,2049]
    const float* lb  = (const float*)d_in[2];   // [4,1]
    const float* ew  = (const float*)d_in[3];   // [4,1,1]
    const float* ebv = (const float*)d_in[4];   // [4,1]
    const float* rx  = (const float*)d_in[5];   // [4]
    const float* mw  = (const float*)d_in[6];   // [4,1,1]
    const float* mb  = (const float*)d_in[7];   // [4,1]
    float* out = (float*)d_out;

    f32x4* pre = (f32x4*)d_ws;                              // 2 MiB
    float* hc  = (float*)((char*)d_ws + (size_t)TT * BB * 16);  // 2 KB

    k_gemm0<<<CH_BLOCKS, 256, 0, stream>>>(x, lw, lb, ew, ebv, rx, pre);
    k_mix<<<CH_BLOCKS + 1, 256, 0, stream>>>(x, lw, lb, ew, ebv, rx, mw, mb,
                                             pre, out, hc, 0, CH_WAVES);
    k_mix<<<CH_BLOCKS + 1, 256, 0, stream>>>(x, lw, lb, ew, ebv, rx, mw, mb,
                                             pre, out, hc, CH_T, 2 * CH_WAVES);
    k_mix<<<CH_BLOCKS + 1, 256, 0, stream>>>(x, lw, lb, ew, ebv, rx, mw, mb,
                                             pre, out, hc, 2 * CH_T, 3 * CH_WAVES);
    k_mix<<<1, 256, 0, stream>>>(x, lw, lb, ew, ebv, rx, mw, mb,
                                 pre, out, hc, 3 * CH_T, 0);
}